// Round 5
// baseline (2071.258 us; speedup 1.0000x reference)
//
#include <hip/hip_runtime.h>
#include <hip/hip_bf16.h>

#define N_NODES 100000
#define N_EDGES 1600000
#define IN_DIM  128
#define HID     64
#define BIN_NODES 64
#define NBINS   ((N_NODES + BIN_NODES - 1) / BIN_NODES)   // 1563
#define EB      2048       // edges per block in scatter_sort
#define CAP     2048       // padded per-bin capacity (avg fill 1024, sd ~32)

#define PITCH_IN  152      // bf16 units per LDS row for K=128 (gemm_in staging)
#define ACC_PITCH 68       // f32 units per accumulator row (+4: bank-spread pad)

typedef __attribute__((ext_vector_type(8))) short bf16x8;   // MFMA A/B frag (4 VGPRs)
typedef __attribute__((ext_vector_type(4))) float f32x4;    // MFMA C/D frag

__device__ inline unsigned short f2bf(float f) {
    __hip_bfloat16 b = __float2bfloat16(f);
    return *reinterpret_cast<unsigned short*>(&b);
}

// ---------------------------------------------------------------------------
// Pre-pack W matrices into B-fragment order bf16 + init padded-bin cursors.
// flat = (((kc*4 + nt)*4 + quad)*16 + n16)*8 + j ;  k = kc*32+quad*8+j, n = nt*16+n16
// ---------------------------------------------------------------------------
__global__ void wf_prep_kernel(const float* __restrict__ Wi,
                               const float* __restrict__ W1,
                               const float* __restrict__ W2,
                               const float* __restrict__ W3,
                               unsigned short* __restrict__ wf_in,
                               unsigned short* __restrict__ wf_hid,
                               int* __restrict__ g_bin_cursor) {
    int t = blockIdx.x * 256 + threadIdx.x;
    if (t < NBINS) g_bin_cursor[t] = t * CAP;
    if (t < 8192) {  // Wi: K=128 -> kc in 0..3
        int j = t & 7, n16 = (t >> 3) & 15, quad = (t >> 7) & 3, nt = (t >> 9) & 3, kc = t >> 11;
        int k = kc * 32 + quad * 8 + j, n = nt * 16 + n16;
        wf_in[t] = f2bf(Wi[k * HID + n]);
    }
    if (t < 4096) {  // W1..W3: K=64 -> kc in 0..1
        int j = t & 7, n16 = (t >> 3) & 15, quad = (t >> 7) & 3, nt = (t >> 9) & 3, kc = t >> 11;
        int k = kc * 32 + quad * 8 + j, n = nt * 16 + n16;
        wf_hid[t]        = f2bf(W1[k * HID + n]);
        wf_hid[4096 + t] = f2bf(W2[k * HID + n]);
        wf_hid[8192 + t] = f2bf(W3[k * HID + n]);
    }
}

// ---------------------------------------------------------------------------
// h0 = relu(x @ Wi + bi) via bf16 MFMA. Block = 64 rows, wave = 16 rows.
// ---------------------------------------------------------------------------
__global__ __launch_bounds__(256) void gemm_in_kernel(
        const float* __restrict__ x,
        const unsigned short* __restrict__ wf,   // fragment-order Wi (bf16 bits)
        const float* __restrict__ bi,
        float* __restrict__ h0,
        __hip_bfloat16* __restrict__ hbf) {
    __shared__ unsigned short sX[64 * PITCH_IN];   // 19456 B
    const int tid  = threadIdx.x;
    const int row0 = blockIdx.x * 64;

    // Stage x tile (64 x 128 f32 -> bf16), coalesced float4 reads, 8B LDS writes.
    #pragma unroll
    for (int it = 0; it < 8; ++it) {
        int i  = tid + it * 256;
        int r  = i >> 5;        // 32 float4 per row
        int kq = i & 31;
        int rg = row0 + r;
        float4 v = (rg < N_NODES)
                 ? ((const float4*)x)[(size_t)rg * (IN_DIM / 4) + kq]
                 : make_float4(0.f, 0.f, 0.f, 0.f);
        ushort4 pk;
        pk.x = f2bf(v.x); pk.y = f2bf(v.y); pk.z = f2bf(v.z); pk.w = f2bf(v.w);
        *(ushort4*)(sX + r * PITCH_IN + kq * 4) = pk;
    }
    __syncthreads();

    const int lane = tid & 63;
    const int wid  = tid >> 6;
    const int l16  = lane & 15;
    const int q    = lane >> 4;

    f32x4 acc[4] = {{0,0,0,0},{0,0,0,0},{0,0,0,0},{0,0,0,0}};
    const bf16x8* wf8 = (const bf16x8*)wf;

    #pragma unroll
    for (int kc = 0; kc < 4; ++kc) {
        bf16x8 af = *(const bf16x8*)(sX + (wid * 16 + l16) * PITCH_IN + kc * 32 + q * 8);
        #pragma unroll
        for (int nt = 0; nt < 4; ++nt) {
            bf16x8 bfr = wf8[((kc * 4 + nt) * 4 + q) * 16 + l16];
            acc[nt] = __builtin_amdgcn_mfma_f32_16x16x32_bf16(af, bfr, acc[nt], 0, 0, 0);
        }
    }

    // Epilogue: C/D layout col = lane&15, row = quad*4 + reg  [m89]
    #pragma unroll
    for (int nt = 0; nt < 4; ++nt) {
        float bb = bi[nt * 16 + l16];
        #pragma unroll
        for (int reg = 0; reg < 4; ++reg) {
            int rg = row0 + wid * 16 + q * 4 + reg;
            if (rg < N_NODES) {
                float v = fmaxf(acc[nt][reg] + bb, 0.0f);
                h0 [(size_t)rg * HID + nt * 16 + l16] = v;
                hbf[(size_t)rg * HID + nt * 16 + l16] = __float2bfloat16(v);
            }
        }
    }
}

// ---------------------------------------------------------------------------
// One-pass binned scatter with LDS sort for coalesced output.
// Bin = 64 target nodes (= one MFMA tile). Record: high32 = w bits,
// low32 = (local_tgt<<17) | src  (local_tgt is 6 bits).
// Bins are PADDED (bin b occupies [b*CAP, b*CAP+cnt_b)); g_bin_cursor was
// pre-initialized to b*CAP, so no hist/scan kernels are needed.
// ---------------------------------------------------------------------------
__global__ __launch_bounds__(256) void scatter_sort_kernel(
        const int* __restrict__ src,
        const int* __restrict__ tgt,
        const float* __restrict__ ea,
        int* __restrict__ g_bin_cursor,
        unsigned long long* __restrict__ binned) {
    __shared__ int cnt[NBINS];      // reused as cursor in local scatter
    __shared__ int lstart[NBINS];
    __shared__ int lbase[NBINS];
    __shared__ unsigned long long srec[EB];   // 16 KB
    __shared__ unsigned short sbin[EB];       // 4 KB (NBINS < 65536)
    __shared__ int stot;
    const int tid = threadIdx.x;

    for (int i = tid; i < NBINS; i += 256) cnt[i] = 0;
    __syncthreads();

    const int e0 = blockIdx.x * EB;
    int myb[EB / 256];
    unsigned long long myrec[EB / 256];
    #pragma unroll
    for (int i = 0; i < EB / 256; ++i) {
        int e = e0 + tid + i * 256;
        if (e < N_EDGES) {
            int t = tgt[e];
            int b = t >> 6;
            myb[i] = b;
            myrec[i] = ((unsigned long long)(unsigned)__float_as_int(ea[e]) << 32)
                     | ((unsigned)(t & 63) << 17) | (unsigned)src[e];
            atomicAdd(&cnt[b], 1);
        } else {
            myb[i] = -1;
        }
    }
    __syncthreads();

    // Wave 0: ripple exclusive scan of cnt[0..NBINS) -> lstart
    if (tid < 64) {
        int carry = 0;
        for (int c = 0; c < (NBINS + 63) / 64; ++c) {
            int idx = c * 64 + tid;
            int v = (idx < NBINS) ? cnt[idx] : 0;
            int sc = v;
            #pragma unroll
            for (int d = 1; d < 64; d <<= 1) {
                int t2 = __shfl_up(sc, d);
                if (tid >= d) sc += t2;
            }
            if (idx < NBINS) lstart[idx] = carry + sc - v;
            carry += __shfl(sc, 63);
        }
        if (tid == 0) stot = carry;
    }
    __syncthreads();

    // One global atomic per touched bin for this block's base.
    for (int i = tid; i < NBINS; i += 256)
        if (cnt[i]) lbase[i] = atomicAdd(&g_bin_cursor[i], cnt[i]);
    __syncthreads();
    for (int i = tid; i < NBINS; i += 256) cnt[i] = 0;   // reuse as cursor
    __syncthreads();

    // Local scatter into bin-sorted LDS order.
    #pragma unroll
    for (int i = 0; i < EB / 256; ++i) {
        if (myb[i] >= 0) {
            int r = atomicAdd(&cnt[myb[i]], 1);
            int p = lstart[myb[i]] + r;
            srec[p] = myrec[i];
            sbin[p] = (unsigned short)myb[i];
        }
    }
    __syncthreads();

    // Coalesced-ish output: sorted order -> per-bin contiguous runs.
    const int tot = stot;
    for (int i = tid; i < tot; i += 256) {
        int b = sbin[i];
        binned[(size_t)lbase[b] + (i - lstart[b])] = srec[i];
    }
}

// ---------------------------------------------------------------------------
// FUSED push-mode: a = h + segment_sum(bf16(h)[src] * w) ; hnext = relu(a@W+b).
// Block = one 64-node bin = one MFMA tile. LDS accumulator [64][68] f32,
// initialized with h. Each half-wave (32 lanes) processes one record:
// shfl-broadcast (src,w) from a wave-wide coalesced 64-record chunk, load the
// random hbf[src] row (128B, fully coalesced per half-wave), ds_add_f32 into
// accum. No per-node CSR (offs/counts/pairs) needed at all. Edge-sum order is
// atomic-arrival order (nondeterministic), same as the previous CSR build.
// MFMA A-frags are read straight from the f32 accumulator (float4 + cvt).
// ---------------------------------------------------------------------------
__global__ __launch_bounds__(256) void agg_gemm_kernel(
        const float* __restrict__ h,               // layer-l activations (f32)
        const __hip_bfloat16* __restrict__ hbf_in, // layer-l activations (bf16)
        const int* __restrict__ g_bin_cursor,
        const unsigned long long* __restrict__ binned,
        const unsigned short* __restrict__ wf,     // fragment-order W (bf16 bits)
        const float* __restrict__ b,
        float* __restrict__ hnext,
        __hip_bfloat16* __restrict__ hbf_out,
        const int store_bf) {
    __shared__ float accS[64][ACC_PITCH];          // 17408 B
    const int tid  = threadIdx.x;
    const int bin  = blockIdx.x;
    const int row0 = bin * 64;
    const int lane = tid & 63;
    const int wid  = tid >> 6;

    // ---- Init accumulator with h tile (f32, coalesced) ----
    #pragma unroll
    for (int it = 0; it < 4; ++it) {
        int i  = tid + it * 256;            // 1024 float4 = 64 rows x 16
        int r  = i >> 4;
        int c4 = i & 15;
        int rg = row0 + r;
        float4 v = (rg < N_NODES)
                 ? ((const float4*)h)[(size_t)rg * (HID / 4) + c4]
                 : make_float4(0.f, 0.f, 0.f, 0.f);
        *(float4*)(&accS[r][c4 * 4]) = v;
    }
    __syncthreads();

    // ---- Push-mode edge aggregation ----
    const int ebeg = bin * CAP;
    const int ecnt = g_bin_cursor[bin] - ebeg;
    const int half = lane >> 5;
    const int l32  = lane & 31;
    const unsigned short* hb = (const unsigned short*)hbf_in;

    for (int j0 = wid * 64; j0 < ecnt; j0 += 256) {
        // Wave-wide coalesced 64-record chunk.
        unsigned long long rl = binned[(size_t)ebeg + min(j0 + lane, ecnt - 1)];
        const int nb   = min(64, ecnt - j0);
        const int last = nb - 1;
        for (int i = 0; i < nb; i += 4) {
            int i0 = i + half;          // this half-wave's record, slot A
            int i1 = i + 2 + half;      // slot B
            bool v0 = (i0 <= last);
            bool v1 = (i1 <= last);
            unsigned long long r0 = __shfl(rl, v0 ? i0 : last);
            unsigned long long r1 = __shfl(rl, v1 ? i1 : last);
            int s0  = (int)(r0 & 0x1FFFF);
            int lt0 = (int)((r0 >> 17) & 63);
            int s1  = (int)(r1 & 0x1FFFF);
            int lt1 = (int)((r1 >> 17) & 63);
            float w0 = v0 ? __int_as_float((int)(r0 >> 32)) : 0.0f;
            float w1 = v1 ? __int_as_float((int)(r1 >> 32)) : 0.0f;
            unsigned g0 = *(const unsigned*)(hb + (size_t)s0 * HID + l32 * 2);
            unsigned g1 = *(const unsigned*)(hb + (size_t)s1 * HID + l32 * 2);
            float a0 = w0 * __uint_as_float(g0 << 16);
            float b0 = w0 * __uint_as_float(g0 & 0xFFFF0000u);
            float a1 = w1 * __uint_as_float(g1 << 16);
            float b1 = w1 * __uint_as_float(g1 & 0xFFFF0000u);
            atomicAdd(&accS[lt0][l32 * 2],     a0);
            atomicAdd(&accS[lt0][l32 * 2 + 1], b0);
            atomicAdd(&accS[lt1][l32 * 2],     a1);
            atomicAdd(&accS[lt1][l32 * 2 + 1], b1);
        }
    }
    __syncthreads();

    // ---- 16x16x32 bf16 MFMA (K=64) + relu epilogue ----
    const int l16 = lane & 15;
    const int q   = lane >> 4;

    f32x4 acc[4] = {{0,0,0,0},{0,0,0,0},{0,0,0,0},{0,0,0,0}};
    const bf16x8* wf8 = (const bf16x8*)wf;

    #pragma unroll
    for (int kc = 0; kc < 2; ++kc) {
        const float* ap = &accS[wid * 16 + l16][kc * 32 + q * 8];
        float4 x0 = *(const float4*)(ap);
        float4 x1 = *(const float4*)(ap + 4);
        bf16x8 af;
        af[0] = (short)f2bf(x0.x); af[1] = (short)f2bf(x0.y);
        af[2] = (short)f2bf(x0.z); af[3] = (short)f2bf(x0.w);
        af[4] = (short)f2bf(x1.x); af[5] = (short)f2bf(x1.y);
        af[6] = (short)f2bf(x1.z); af[7] = (short)f2bf(x1.w);
        #pragma unroll
        for (int nt = 0; nt < 4; ++nt) {
            bf16x8 bfr = wf8[((kc * 4 + nt) * 4 + q) * 16 + l16];
            acc[nt] = __builtin_amdgcn_mfma_f32_16x16x32_bf16(af, bfr, acc[nt], 0, 0, 0);
        }
    }

    #pragma unroll
    for (int nt = 0; nt < 4; ++nt) {
        float bb = b[nt * 16 + l16];
        #pragma unroll
        for (int reg = 0; reg < 4; ++reg) {
            int rg = row0 + wid * 16 + q * 4 + reg;
            if (rg < N_NODES) {
                float v = fmaxf(acc[nt][reg] + bb, 0.0f);
                hnext[(size_t)rg * HID + nt * 16 + l16] = v;
                if (store_bf)
                    hbf_out[(size_t)rg * HID + nt * 16 + l16] = __float2bfloat16(v);
            }
        }
    }
}

extern "C" void kernel_launch(void* const* d_in, const int* in_sizes, int n_in,
                              void* d_out, int out_size, void* d_ws, size_t ws_size,
                              hipStream_t stream) {
    const float* x   = (const float*)d_in[0];
    const int*   ei  = (const int*)  d_in[1];   // (2, E): [src | tgt]
    const float* ea  = (const float*)d_in[2];
    const float* Wi  = (const float*)d_in[3];
    const float* bi  = (const float*)d_in[4];
    const float* W1  = (const float*)d_in[5];
    const float* b1  = (const float*)d_in[6];
    const float* W2  = (const float*)d_in[7];
    const float* b2  = (const float*)d_in[8];
    const float* W3  = (const float*)d_in[9];
    const float* b3  = (const float*)d_in[10];
    const float* bl[3] = { b1, b2, b3 };
    float* out = (float*)d_out;  // (4, N, HID)

    const int* src = ei;
    const int* tgt = ei + N_EDGES;

    // Workspace layout (padded bins; no pairs/offs/counts; hbf double-buffered).
    unsigned long long* binned = (unsigned long long*)d_ws;          // NBINS*CAP*8B (25.6 MB)
    int* g_bin_cursor = (int*)(binned + (size_t)NBINS * CAP);
    __hip_bfloat16* hbf0 = (__hip_bfloat16*)(g_bin_cursor + NBINS + 1);
    __hip_bfloat16* hbf1 = hbf0 + (size_t)N_NODES * HID;             // N*HID bf16
    unsigned short* wf_in  = (unsigned short*)(hbf1 + (size_t)N_NODES * HID);
    unsigned short* wf_hid = wf_in + 8192;                           // 3 x 4096

    wf_prep_kernel<<<32, 256, 0, stream>>>(Wi, W1, W2, W3, wf_in, wf_hid,
                                           g_bin_cursor);

    const int eb_blocks = (N_EDGES + EB - 1) / EB;  // 782
    scatter_sort_kernel<<<eb_blocks, 256, 0, stream>>>(src, tgt, ea,
                                                       g_bin_cursor, binned);

    const int gemm_blocks = (N_NODES + 63) / 64;    // 1563 == NBINS
    gemm_in_kernel<<<gemm_blocks, 256, 0, stream>>>(x, wf_in, bi, out, hbf0);

    __hip_bfloat16* hin  = hbf0;
    __hip_bfloat16* hout = hbf1;
    for (int l = 0; l < 3; ++l) {
        const float* hl = out + (size_t)l * N_NODES * HID;
        float* hn       = out + (size_t)(l + 1) * N_NODES * HID;
        agg_gemm_kernel<<<NBINS, 256, 0, stream>>>(
            hl, hin, g_bin_cursor, binned,
            wf_hid + (size_t)l * 4096, bl[l], hn, hout, (l < 2) ? 1 : 0);
        __hip_bfloat16* t = hin; hin = hout; hout = t;
    }
}

// Round 6
// 419.328 us; speedup vs baseline: 4.9395x; 4.9395x over previous
//
#include <hip/hip_runtime.h>
#include <hip/hip_bf16.h>

#define N_NODES 100000
#define N_EDGES 1600000
#define IN_DIM  128
#define HID     64
#define BIN_NODES 64
#define NBINS   ((N_NODES + BIN_NODES - 1) / BIN_NODES)   // 1563
#define EB      2048       // edges per block in the scatter branch
#define EB_BLOCKS ((N_EDGES + EB - 1) / EB)               // 782
#define CAP     2048       // padded per-bin capacity (avg fill 1024, sd ~32)

#define PITCH_IN  152      // bf16 units per LDS row for K=128 (gemm_in staging)
#define PITCH_HID 88       // bf16 units per LDS row for K=64  (agg staging)

typedef __attribute__((ext_vector_type(8))) short bf16x8;   // MFMA A/B frag (4 VGPRs)
typedef __attribute__((ext_vector_type(4))) float f32x4;    // MFMA C/D frag

__device__ inline unsigned short f2bf(float f) {
    __hip_bfloat16 b = __float2bfloat16(f);
    return *reinterpret_cast<unsigned short*>(&b);
}

// ---------------------------------------------------------------------------
// Pre-pack W matrices into B-fragment order bf16 + init padded-bin cursors.
// flat = (((kc*4 + nt)*4 + quad)*16 + n16)*8 + j ;  k = kc*32+quad*8+j, n = nt*16+n16
// ---------------------------------------------------------------------------
__global__ void wf_prep_kernel(const float* __restrict__ Wi,
                               const float* __restrict__ W1,
                               const float* __restrict__ W2,
                               const float* __restrict__ W3,
                               unsigned short* __restrict__ wf_in,
                               unsigned short* __restrict__ wf_hid,
                               int* __restrict__ g_bin_cursor) {
    int t = blockIdx.x * 256 + threadIdx.x;
    if (t < NBINS) g_bin_cursor[t] = t * CAP;
    if (t < 8192) {  // Wi: K=128 -> kc in 0..3
        int j = t & 7, n16 = (t >> 3) & 15, quad = (t >> 7) & 3, nt = (t >> 9) & 3, kc = t >> 11;
        int k = kc * 32 + quad * 8 + j, n = nt * 16 + n16;
        wf_in[t] = f2bf(Wi[k * HID + n]);
    }
    if (t < 4096) {  // W1..W3: K=64 -> kc in 0..1
        int j = t & 7, n16 = (t >> 3) & 15, quad = (t >> 7) & 3, nt = (t >> 9) & 3, kc = t >> 11;
        int k = kc * 32 + quad * 8 + j, n = nt * 16 + n16;
        wf_hid[t]        = f2bf(W1[k * HID + n]);
        wf_hid[4096 + t] = f2bf(W2[k * HID + n]);
        wf_hid[8192 + t] = f2bf(W3[k * HID + n]);
    }
}

// ---------------------------------------------------------------------------
// Fused prep: blocks [0, EB_BLOCKS) run the binned edge scatter (atomic /
// LDS-sort bound); blocks [EB_BLOCKS, EB_BLOCKS+gemm) run h0 = relu(x@Wi+bi)
// (BW / MFMA bound). Independent work, disjoint LDS use (union), overlapped
// in one launch so the BW kernel hides under the atomic kernel.
// Record: high32 = w bits, low32 = (local_tgt<<17) | src (local_tgt 6 bits).
// ---------------------------------------------------------------------------
struct ScatterS {
    unsigned long long srec[EB];   // 16384 B (8B-aligned first)
    unsigned short sbin[EB];       //  4096 B
    int cnt[NBINS];                //  6252 B
    int lstart[NBINS];             //  6252 B
    int lbase[NBINS];              //  6252 B
    int stot;
};
struct GemmS {
    unsigned short sX[64 * PITCH_IN];   // 19456 B
};

__global__ __launch_bounds__(256) void fused_prep_kernel(
        const int* __restrict__ src,
        const int* __restrict__ tgt,
        const float* __restrict__ ea,
        int* __restrict__ g_bin_cursor,
        unsigned long long* __restrict__ binned,
        const float* __restrict__ x,
        const unsigned short* __restrict__ wf,
        const float* __restrict__ bi,
        float* __restrict__ h0,
        __hip_bfloat16* __restrict__ hbf) {
    __shared__ __align__(16) unsigned char smem[sizeof(ScatterS)];
    const int tid = threadIdx.x;

    if (blockIdx.x < EB_BLOCKS) {
        // ================= scatter branch =================
        ScatterS* S = reinterpret_cast<ScatterS*>(smem);
        for (int i = tid; i < NBINS; i += 256) S->cnt[i] = 0;
        __syncthreads();

        const int e0 = blockIdx.x * EB;
        int myb[EB / 256];
        unsigned long long myrec[EB / 256];
        #pragma unroll
        for (int i = 0; i < EB / 256; ++i) {
            int e = e0 + tid + i * 256;
            if (e < N_EDGES) {
                int t = tgt[e];
                int b = t >> 6;
                myb[i] = b;
                myrec[i] = ((unsigned long long)(unsigned)__float_as_int(ea[e]) << 32)
                         | ((unsigned)(t & 63) << 17) | (unsigned)src[e];
                atomicAdd(&S->cnt[b], 1);
            } else {
                myb[i] = -1;
            }
        }
        __syncthreads();

        // Wave 0: ripple exclusive scan of cnt[0..NBINS) -> lstart
        if (tid < 64) {
            int carry = 0;
            for (int c = 0; c < (NBINS + 63) / 64; ++c) {
                int idx = c * 64 + tid;
                int v = (idx < NBINS) ? S->cnt[idx] : 0;
                int sc = v;
                #pragma unroll
                for (int d = 1; d < 64; d <<= 1) {
                    int t2 = __shfl_up(sc, d);
                    if (tid >= d) sc += t2;
                }
                if (idx < NBINS) S->lstart[idx] = carry + sc - v;
                carry += __shfl(sc, 63);
            }
            if (tid == 0) S->stot = carry;
        }
        __syncthreads();

        // One global atomic per touched bin for this block's base.
        for (int i = tid; i < NBINS; i += 256)
            if (S->cnt[i]) S->lbase[i] = atomicAdd(&g_bin_cursor[i], S->cnt[i]);
        __syncthreads();
        for (int i = tid; i < NBINS; i += 256) S->cnt[i] = 0;   // reuse as cursor
        __syncthreads();

        // Local scatter into bin-sorted LDS order.
        #pragma unroll
        for (int i = 0; i < EB / 256; ++i) {
            if (myb[i] >= 0) {
                int r = atomicAdd(&S->cnt[myb[i]], 1);
                int p = S->lstart[myb[i]] + r;
                S->srec[p] = myrec[i];
                S->sbin[p] = (unsigned short)myb[i];
            }
        }
        __syncthreads();

        // Output in sorted order -> per-bin contiguous runs.
        const int tot = S->stot;
        for (int i = tid; i < tot; i += 256) {
            int b = S->sbin[i];
            binned[(size_t)S->lbase[b] + (i - S->lstart[b])] = S->srec[i];
        }
    } else {
        // ================= gemm_in branch =================
        GemmS* G = reinterpret_cast<GemmS*>(smem);
        const int row0 = (blockIdx.x - EB_BLOCKS) * 64;

        #pragma unroll
        for (int it = 0; it < 8; ++it) {
            int i  = tid + it * 256;
            int r  = i >> 5;        // 32 float4 per row
            int kq = i & 31;
            int rg = row0 + r;
            float4 v = (rg < N_NODES)
                     ? ((const float4*)x)[(size_t)rg * (IN_DIM / 4) + kq]
                     : make_float4(0.f, 0.f, 0.f, 0.f);
            ushort4 pk;
            pk.x = f2bf(v.x); pk.y = f2bf(v.y); pk.z = f2bf(v.z); pk.w = f2bf(v.w);
            *(ushort4*)(G->sX + r * PITCH_IN + kq * 4) = pk;
        }
        __syncthreads();

        const int lane = tid & 63;
        const int wid  = tid >> 6;
        const int l16  = lane & 15;
        const int q    = lane >> 4;

        f32x4 acc[4] = {{0,0,0,0},{0,0,0,0},{0,0,0,0},{0,0,0,0}};
        const bf16x8* wf8 = (const bf16x8*)wf;

        #pragma unroll
        for (int kc = 0; kc < 4; ++kc) {
            bf16x8 af = *(const bf16x8*)(G->sX + (wid * 16 + l16) * PITCH_IN + kc * 32 + q * 8);
            #pragma unroll
            for (int nt = 0; nt < 4; ++nt) {
                bf16x8 bfr = wf8[((kc * 4 + nt) * 4 + q) * 16 + l16];
                acc[nt] = __builtin_amdgcn_mfma_f32_16x16x32_bf16(af, bfr, acc[nt], 0, 0, 0);
            }
        }

        // Epilogue: C/D layout col = lane&15, row = quad*4 + reg  [m89]
        #pragma unroll
        for (int nt = 0; nt < 4; ++nt) {
            float bb = bi[nt * 16 + l16];
            #pragma unroll
            for (int reg = 0; reg < 4; ++reg) {
                int rg = row0 + wid * 16 + q * 4 + reg;
                if (rg < N_NODES) {
                    float v = fmaxf(acc[nt][reg] + bb, 0.0f);
                    h0 [(size_t)rg * HID + nt * 16 + l16] = v;
                    hbf[(size_t)rg * HID + nt * 16 + l16] = __float2bfloat16(v);
                }
            }
        }
    }
}

// ---------------------------------------------------------------------------
// FUSED: a = h + segment_sum(bf16(h)[src] * w) ; hnext = relu(a @ W + b).
// Block = one 64-node bin = one MFMA tile.
// Step 1: sort this bin's records by local target in LDS (histogram ->
//         64-lane scan -> scatter). This replaces the old fine_fill kernel
//         and the global `pairs` array entirely.
// Step 2: R4's proven pull-mode gather (2 edges in flight per 16-lane group,
//         128B coalesced row loads), with the per-edge (src,w) now read via
//         same-address LDS broadcast (free) instead of global load + shfl.
// Step 3: 16x16x32 bf16 MFMA (K=64) + relu epilogue.
// NO per-element LDS atomics in the accumulation path (R5's mistake).
// ---------------------------------------------------------------------------
__global__ __launch_bounds__(256) void agg_gemm_kernel(
        const float* __restrict__ h,               // layer-l activations (f32)
        const __hip_bfloat16* __restrict__ hbf_in, // layer-l activations (bf16)
        const int* __restrict__ g_bin_cursor,
        const unsigned long long* __restrict__ binned,
        const unsigned short* __restrict__ wf,     // fragment-order W (bf16 bits)
        const float* __restrict__ b,
        float* __restrict__ hnext,
        __hip_bfloat16* __restrict__ hbf_out,
        const int store_bf) {
    __shared__ int2 sp[CAP];                       // 16384 B sorted (src, w)
    __shared__ unsigned short sXs[64 * PITCH_HID]; // 11264 B
    __shared__ int nbase[64], ncur[64], scnt[64];
    const int tid  = threadIdx.x;
    const int bin  = blockIdx.x;
    const int row0 = bin * 64;
    const int lane = tid & 63;
    const int wid  = tid >> 6;
    const int grp  = lane >> 4;
    const int sub  = lane & 15;
    const int ebeg = bin * CAP;
    const int ecnt = g_bin_cursor[bin] - ebeg;

    // ---- Step 1a: histogram of local targets ----
    if (tid < 64) ncur[tid] = 0;
    __syncthreads();
    for (int i = tid; i < ecnt; i += 256)
        atomicAdd(&ncur[(int)((binned[ebeg + i] >> 17) & 63)], 1);
    __syncthreads();

    // ---- Step 1b: 64-lane exclusive scan (wave 0) ----
    if (tid < 64) {
        int v = ncur[tid], sc = v;
        #pragma unroll
        for (int d = 1; d < 64; d <<= 1) {
            int t2 = __shfl_up(sc, d);
            if (tid >= d) sc += t2;
        }
        nbase[tid] = sc - v;
        scnt[tid]  = v;
        ncur[tid]  = sc - v;   // running cursor starts at base
    }
    __syncthreads();

    // ---- Step 1c: scatter records into per-node sorted LDS order ----
    for (int i = tid; i < ecnt; i += 256) {
        unsigned long long rec = binned[ebeg + i];   // L2-hot (just read above)
        int lt = (int)((rec >> 17) & 63);
        int r  = atomicAdd(&ncur[lt], 1);
        sp[r] = make_int2((int)(rec & 0x1FFFF), (int)(rec >> 32));
    }
    __syncthreads();

    // ---- Step 2: pull-mode gather, 16 nodes per wave ----
    for (int t = 0; t < 16; ++t) {
        const int lt   = wid * 16 + t;
        const int node = row0 + lt;
        if (node < N_NODES) {
            const int beg = nbase[lt];
            const int cnt = scnt[lt];
            float ax = 0.f, ay = 0.f, az = 0.f, aw = 0.f;
            const int last = cnt - 1;
            for (int i = 0; i < cnt; i += 8) {
                int e0 = i + grp;
                int e1 = i + 4 + grp;
                bool l0 = (e0 <= last);
                bool l1 = (e1 <= last);
                int2 p0 = sp[beg + (l0 ? e0 : last)];   // 16-lane same-addr broadcast
                int2 p1 = sp[beg + (l1 ? e1 : last)];
                uint2 g0 = *(const uint2*)(hbf_in + (size_t)p0.x * HID + sub * 4);
                uint2 g1 = *(const uint2*)(hbf_in + (size_t)p1.x * HID + sub * 4);
                float w0 = l0 ? __int_as_float(p0.y) : 0.0f;
                float w1 = l1 ? __int_as_float(p1.y) : 0.0f;
                ax += w0 * __uint_as_float(g0.x << 16);
                ay += w0 * __uint_as_float(g0.x & 0xFFFF0000u);
                az += w0 * __uint_as_float(g0.y << 16);
                aw += w0 * __uint_as_float(g0.y & 0xFFFF0000u);
                ax += w1 * __uint_as_float(g1.x << 16);
                ay += w1 * __uint_as_float(g1.x & 0xFFFF0000u);
                az += w1 * __uint_as_float(g1.y << 16);
                aw += w1 * __uint_as_float(g1.y & 0xFFFF0000u);
            }
            ax += __shfl_xor(ax, 16); ay += __shfl_xor(ay, 16);
            az += __shfl_xor(az, 16); aw += __shfl_xor(aw, 16);
            ax += __shfl_xor(ax, 32); ay += __shfl_xor(ay, 32);
            az += __shfl_xor(az, 32); aw += __shfl_xor(aw, 32);
            if (grp == 0) {
                const float4 hv = *(const float4*)(h + (size_t)node * HID + sub * 4);
                ushort4 pk;
                pk.x = f2bf(hv.x + ax); pk.y = f2bf(hv.y + ay);
                pk.z = f2bf(hv.z + az); pk.w = f2bf(hv.w + aw);
                *(ushort4*)(sXs + lt * PITCH_HID + sub * 4) = pk;
            }
        } else if (grp == 0) {
            ushort4 z; z.x = 0; z.y = 0; z.z = 0; z.w = 0;
            *(ushort4*)(sXs + lt * PITCH_HID + sub * 4) = z;
        }
    }
    __syncthreads();

    // ---- Step 3: 16x16x32 bf16 MFMA (K=64) + relu epilogue ----
    const int l16 = lane & 15;
    const int q   = lane >> 4;

    f32x4 acc[4] = {{0,0,0,0},{0,0,0,0},{0,0,0,0},{0,0,0,0}};
    const bf16x8* wf8 = (const bf16x8*)wf;

    #pragma unroll
    for (int kc = 0; kc < 2; ++kc) {
        bf16x8 af = *(const bf16x8*)(sXs + (wid * 16 + l16) * PITCH_HID + kc * 32 + q * 8);
        #pragma unroll
        for (int nt = 0; nt < 4; ++nt) {
            bf16x8 bfr = wf8[((kc * 4 + nt) * 4 + q) * 16 + l16];
            acc[nt] = __builtin_amdgcn_mfma_f32_16x16x32_bf16(af, bfr, acc[nt], 0, 0, 0);
        }
    }

    #pragma unroll
    for (int nt = 0; nt < 4; ++nt) {
        float bb = b[nt * 16 + l16];
        #pragma unroll
        for (int reg = 0; reg < 4; ++reg) {
            int rg = row0 + wid * 16 + q * 4 + reg;
            if (rg < N_NODES) {
                float v = fmaxf(acc[nt][reg] + bb, 0.0f);
                hnext[(size_t)rg * HID + nt * 16 + l16] = v;
                if (store_bf)
                    hbf_out[(size_t)rg * HID + nt * 16 + l16] = __float2bfloat16(v);
            }
        }
    }
}

extern "C" void kernel_launch(void* const* d_in, const int* in_sizes, int n_in,
                              void* d_out, int out_size, void* d_ws, size_t ws_size,
                              hipStream_t stream) {
    const float* x   = (const float*)d_in[0];
    const int*   ei  = (const int*)  d_in[1];   // (2, E): [src | tgt]
    const float* ea  = (const float*)d_in[2];
    const float* Wi  = (const float*)d_in[3];
    const float* bi  = (const float*)d_in[4];
    const float* W1  = (const float*)d_in[5];
    const float* b1  = (const float*)d_in[6];
    const float* W2  = (const float*)d_in[7];
    const float* b2  = (const float*)d_in[8];
    const float* W3  = (const float*)d_in[9];
    const float* b3  = (const float*)d_in[10];
    const float* bl[3] = { b1, b2, b3 };
    float* out = (float*)d_out;  // (4, N, HID)

    const int* src = ei;
    const int* tgt = ei + N_EDGES;

    // Workspace layout (padded bins; no pairs/offs/counts; hbf double-buffered).
    unsigned long long* binned = (unsigned long long*)d_ws;          // NBINS*CAP*8B (25.6 MB)
    int* g_bin_cursor = (int*)(binned + (size_t)NBINS * CAP);
    __hip_bfloat16* hbf0 = (__hip_bfloat16*)(g_bin_cursor + NBINS + 1);
    __hip_bfloat16* hbf1 = hbf0 + (size_t)N_NODES * HID;             // N*HID bf16
    unsigned short* wf_in  = (unsigned short*)(hbf1 + (size_t)N_NODES * HID);
    unsigned short* wf_hid = wf_in + 8192;                           // 3 x 4096

    wf_prep_kernel<<<32, 256, 0, stream>>>(Wi, W1, W2, W3, wf_in, wf_hid,
                                           g_bin_cursor);

    const int gemm_blocks = (N_NODES + 63) / 64;    // 1563 == NBINS
    fused_prep_kernel<<<EB_BLOCKS + gemm_blocks, 256, 0, stream>>>(
        src, tgt, ea, g_bin_cursor, binned,
        x, wf_in, bi, out, hbf0);

    __hip_bfloat16* hin  = hbf0;
    __hip_bfloat16* hout = hbf1;
    for (int l = 0; l < 3; ++l) {
        const float* hl = out + (size_t)l * N_NODES * HID;
        float* hn       = out + (size_t)(l + 1) * N_NODES * HID;
        agg_gemm_kernel<<<NBINS, 256, 0, stream>>>(
            hl, hin, g_bin_cursor, binned,
            wf_hid + (size_t)l * 4096, bl[l], hn, hout, (l < 2) ? 1 : 0);
        __hip_bfloat16* t = hin; hin = hout; hout = t;
    }
}

// Round 7
// 409.519 us; speedup vs baseline: 5.0578x; 1.0240x over previous
//
#include <hip/hip_runtime.h>
#include <hip/hip_bf16.h>

#define N_NODES 100000
#define N_EDGES 1600000
#define IN_DIM  128
#define HID     64
#define CAP_N   64         // padded per-NODE capacity (avg degree 16, P(deg>=64)~1e-18)

#define PITCH_IN  152      // bf16 units per LDS row for K=128 (gemm_in staging)
#define PITCH_HID 88       // bf16 units per LDS row for K=64  (agg staging)

typedef __attribute__((ext_vector_type(8))) short bf16x8;   // MFMA A/B frag (4 VGPRs)
typedef __attribute__((ext_vector_type(4))) float f32x4;    // MFMA C/D frag

__device__ inline unsigned short f2bf(float f) {
    __hip_bfloat16 b = __float2bfloat16(f);
    return *reinterpret_cast<unsigned short*>(&b);
}

// ---------------------------------------------------------------------------
// Pre-pack W matrices into B-fragment order bf16 + zero per-node counters.
// flat = (((kc*4 + nt)*4 + quad)*16 + n16)*8 + j ;  k = kc*32+quad*8+j, n = nt*16+n16
// Grid: 391 blocks x 256 (covers N_NODES for the counter init).
// ---------------------------------------------------------------------------
__global__ void wf_prep_kernel(const float* __restrict__ Wi,
                               const float* __restrict__ W1,
                               const float* __restrict__ W2,
                               const float* __restrict__ W3,
                               unsigned short* __restrict__ wf_in,
                               unsigned short* __restrict__ wf_hid,
                               int* __restrict__ cnt) {
    int t = blockIdx.x * 256 + threadIdx.x;
    if (t < N_NODES) cnt[t] = 0;
    if (t < 8192) {  // Wi: K=128 -> kc in 0..3
        int j = t & 7, n16 = (t >> 3) & 15, quad = (t >> 7) & 3, nt = (t >> 9) & 3, kc = t >> 11;
        int k = kc * 32 + quad * 8 + j, n = nt * 16 + n16;
        wf_in[t] = f2bf(Wi[k * HID + n]);
    }
    if (t < 4096) {  // W1..W3: K=64 -> kc in 0..1
        int j = t & 7, n16 = (t >> 3) & 15, quad = (t >> 7) & 3, nt = (t >> 9) & 3, kc = t >> 11;
        int k = kc * 32 + quad * 8 + j, n = nt * 16 + n16;
        wf_hid[t]        = f2bf(W1[k * HID + n]);
        wf_hid[4096 + t] = f2bf(W2[k * HID + n]);
        wf_hid[8192 + t] = f2bf(W3[k * HID + n]);
    }
}

// ---------------------------------------------------------------------------
// Direct per-node scatter: the ENTIRE CSR build in one pass.
// binned[node*CAP_N + r] = (src, w_bits), r from a per-node atomic counter.
// Atomics spread over 100K counters (6250 cache lines) -> low contention.
// Replaces bin_hist/bin_scan/bin_scatter/fine_fill/scatter_sort entirely.
// ---------------------------------------------------------------------------
__global__ __launch_bounds__(256) void scatter_direct_kernel(
        const int* __restrict__ src,
        const int* __restrict__ tgt,
        const float* __restrict__ ea,
        int* __restrict__ cnt,
        int2* __restrict__ binned) {
    int e = blockIdx.x * 256 + threadIdx.x;
    if (e < N_EDGES) {
        int t = tgt[e];
        int r = atomicAdd(&cnt[t], 1);
        if (r < CAP_N)   // overflow guard (P ~ 1e-13); dropped edge would fail test
            binned[(size_t)t * CAP_N + r] = make_int2(src[e], __float_as_int(ea[e]));
    }
}

// ---------------------------------------------------------------------------
// h0 = relu(x @ Wi + bi) via bf16 MFMA. Block = 64 rows, wave = 16 rows.
// ---------------------------------------------------------------------------
__global__ __launch_bounds__(256) void gemm_in_kernel(
        const float* __restrict__ x,
        const unsigned short* __restrict__ wf,   // fragment-order Wi (bf16 bits)
        const float* __restrict__ bi,
        float* __restrict__ h0,
        __hip_bfloat16* __restrict__ hbf) {
    __shared__ unsigned short sX[64 * PITCH_IN];   // 19456 B
    const int tid  = threadIdx.x;
    const int row0 = blockIdx.x * 64;

    // Stage x tile (64 x 128 f32 -> bf16), coalesced float4 reads, 8B LDS writes.
    #pragma unroll
    for (int it = 0; it < 8; ++it) {
        int i  = tid + it * 256;
        int r  = i >> 5;        // 32 float4 per row
        int kq = i & 31;
        int rg = row0 + r;
        float4 v = (rg < N_NODES)
                 ? ((const float4*)x)[(size_t)rg * (IN_DIM / 4) + kq]
                 : make_float4(0.f, 0.f, 0.f, 0.f);
        ushort4 pk;
        pk.x = f2bf(v.x); pk.y = f2bf(v.y); pk.z = f2bf(v.z); pk.w = f2bf(v.w);
        *(ushort4*)(sX + r * PITCH_IN + kq * 4) = pk;
    }
    __syncthreads();

    const int lane = tid & 63;
    const int wid  = tid >> 6;
    const int l16  = lane & 15;
    const int q    = lane >> 4;

    f32x4 acc[4] = {{0,0,0,0},{0,0,0,0},{0,0,0,0},{0,0,0,0}};
    const bf16x8* wf8 = (const bf16x8*)wf;

    #pragma unroll
    for (int kc = 0; kc < 4; ++kc) {
        bf16x8 af = *(const bf16x8*)(sX + (wid * 16 + l16) * PITCH_IN + kc * 32 + q * 8);
        #pragma unroll
        for (int nt = 0; nt < 4; ++nt) {
            bf16x8 bfr = wf8[((kc * 4 + nt) * 4 + q) * 16 + l16];
            acc[nt] = __builtin_amdgcn_mfma_f32_16x16x32_bf16(af, bfr, acc[nt], 0, 0, 0);
        }
    }

    // Epilogue: C/D layout col = lane&15, row = quad*4 + reg  [m89]
    #pragma unroll
    for (int nt = 0; nt < 4; ++nt) {
        float bb = bi[nt * 16 + l16];
        #pragma unroll
        for (int reg = 0; reg < 4; ++reg) {
            int rg = row0 + wid * 16 + q * 4 + reg;
            if (rg < N_NODES) {
                float v = fmaxf(acc[nt][reg] + bb, 0.0f);
                h0 [(size_t)rg * HID + nt * 16 + l16] = v;
                hbf[(size_t)rg * HID + nt * 16 + l16] = __float2bfloat16(v);
            }
        }
    }
}

// ---------------------------------------------------------------------------
// FUSED: a = h + segment_sum(bf16(h)[src] * w) ; hnext = relu(a @ W + b).
// R4's proven pull-mode structure, now reading the per-node PADDED edge array
// directly (beg = node*CAP_N): no offs, no pairs, no sort anywhere.
//  - per-wave counts loaded ONCE (lanes 0-15) and shfl-broadcast (no per-node
//    dependent scalar loads)
//  - wave-wide coalesced pair prefetch for node t+1 issued before node t's
//    gather, clamped to min(lane, cnt-1) so only needed lines are fetched
//  - 2 edges in flight per 16-lane group, 128B coalesced hbf row loads
// ---------------------------------------------------------------------------
__global__ __launch_bounds__(256) void agg_gemm_kernel(
        const float* __restrict__ h,               // layer-l activations (f32)
        const __hip_bfloat16* __restrict__ hbf_in, // layer-l activations (bf16)
        const int* __restrict__ cnt,
        const int2* __restrict__ binned,
        const unsigned short* __restrict__ wf,     // fragment-order W (bf16 bits)
        const float* __restrict__ b,
        float* __restrict__ hnext,
        __hip_bfloat16* __restrict__ hbf_out,
        const int store_bf) {
    __shared__ unsigned short sXs[64 * PITCH_HID]; // 11264 B
    const int tid  = threadIdx.x;
    const int row0 = blockIdx.x * 64;
    const int lane = tid & 63;
    const int wid  = tid >> 6;
    const int grp  = lane >> 4;
    const int sub  = lane & 15;

    const int node0 = row0 + wid * 16;

    // Counts for this wave's 16 nodes: one coalesced load, shfl-broadcast.
    int cv = 0;
    {
        int nl = node0 + (lane & 15);
        if (lane < 16 && nl < N_NODES) cv = min(cnt[nl], CAP_N);
    }

    // Prefetch node0's pair block (clamped: only lines covering [0,cnt) fetched).
    int c0 = __shfl(cv, 0);
    int2 pl = binned[(size_t)min(node0, N_NODES - 1) * CAP_N + min(lane, max(c0 - 1, 0))];

    // ---- Phase 1: aggregate 16 nodes per wave into LDS (bf16) ----
    for (int t = 0; t < 16; ++t) {
        const int node = node0 + t;                // wave-uniform
        const int ccur = __shfl(cv, t);
        const int2 pl_cur = pl;
        if (t < 15) {                              // prefetch next node's pairs
            int cn = __shfl(cv, t + 1);
            pl = binned[(size_t)min(node + 1, N_NODES - 1) * CAP_N
                        + min(lane, max(cn - 1, 0))];
        }
        if (node < N_NODES) {
            float ax = 0.f, ay = 0.f, az = 0.f, aw = 0.f;
            const int last = ccur - 1;
            for (int i = 0; i < ccur; i += 8) {
                int e0 = i + grp;
                int e1 = i + 4 + grp;
                bool l0 = (e0 <= last);
                bool l1 = (e1 <= last);
                int s0  = __shfl(pl_cur.x, l0 ? e0 : last);
                int w0i = __shfl(pl_cur.y, l0 ? e0 : last);
                int s1  = __shfl(pl_cur.x, l1 ? e1 : last);
                int w1i = __shfl(pl_cur.y, l1 ? e1 : last);
                uint2 g0 = *(const uint2*)(hbf_in + (size_t)s0 * HID + sub * 4);
                uint2 g1 = *(const uint2*)(hbf_in + (size_t)s1 * HID + sub * 4);
                float w0 = l0 ? __int_as_float(w0i) : 0.0f;
                float w1 = l1 ? __int_as_float(w1i) : 0.0f;
                ax += w0 * __uint_as_float(g0.x << 16);
                ay += w0 * __uint_as_float(g0.x & 0xFFFF0000u);
                az += w0 * __uint_as_float(g0.y << 16);
                aw += w0 * __uint_as_float(g0.y & 0xFFFF0000u);
                ax += w1 * __uint_as_float(g1.x << 16);
                ay += w1 * __uint_as_float(g1.x & 0xFFFF0000u);
                az += w1 * __uint_as_float(g1.y << 16);
                aw += w1 * __uint_as_float(g1.y & 0xFFFF0000u);
            }
            ax += __shfl_xor(ax, 16); ay += __shfl_xor(ay, 16);
            az += __shfl_xor(az, 16); aw += __shfl_xor(aw, 16);
            ax += __shfl_xor(ax, 32); ay += __shfl_xor(ay, 32);
            az += __shfl_xor(az, 32); aw += __shfl_xor(aw, 32);
            if (grp == 0) {
                const float4 hv = *(const float4*)(h + (size_t)node * HID + sub * 4);
                ushort4 pk;
                pk.x = f2bf(hv.x + ax); pk.y = f2bf(hv.y + ay);
                pk.z = f2bf(hv.z + az); pk.w = f2bf(hv.w + aw);
                *(ushort4*)(sXs + (wid * 16 + t) * PITCH_HID + sub * 4) = pk;
            }
        } else if (grp == 0) {
            ushort4 z; z.x = 0; z.y = 0; z.z = 0; z.w = 0;
            *(ushort4*)(sXs + (wid * 16 + t) * PITCH_HID + sub * 4) = z;
        }
    }
    __syncthreads();

    // ---- Phase 2: 16x16x32 bf16 MFMA (K=64) + relu epilogue ----
    const int l16 = lane & 15;
    const int q   = lane >> 4;

    f32x4 acc[4] = {{0,0,0,0},{0,0,0,0},{0,0,0,0},{0,0,0,0}};
    const bf16x8* wf8 = (const bf16x8*)wf;

    #pragma unroll
    for (int kc = 0; kc < 2; ++kc) {
        bf16x8 af = *(const bf16x8*)(sXs + (wid * 16 + l16) * PITCH_HID + kc * 32 + q * 8);
        #pragma unroll
        for (int nt = 0; nt < 4; ++nt) {
            bf16x8 bfr = wf8[((kc * 4 + nt) * 4 + q) * 16 + l16];
            acc[nt] = __builtin_amdgcn_mfma_f32_16x16x32_bf16(af, bfr, acc[nt], 0, 0, 0);
        }
    }

    #pragma unroll
    for (int nt = 0; nt < 4; ++nt) {
        float bb = b[nt * 16 + l16];
        #pragma unroll
        for (int reg = 0; reg < 4; ++reg) {
            int rg = row0 + wid * 16 + q * 4 + reg;
            if (rg < N_NODES) {
                float v = fmaxf(acc[nt][reg] + bb, 0.0f);
                hnext[(size_t)rg * HID + nt * 16 + l16] = v;
                if (store_bf)
                    hbf_out[(size_t)rg * HID + nt * 16 + l16] = __float2bfloat16(v);
            }
        }
    }
}

extern "C" void kernel_launch(void* const* d_in, const int* in_sizes, int n_in,
                              void* d_out, int out_size, void* d_ws, size_t ws_size,
                              hipStream_t stream) {
    const float* x   = (const float*)d_in[0];
    const int*   ei  = (const int*)  d_in[1];   // (2, E): [src | tgt]
    const float* ea  = (const float*)d_in[2];
    const float* Wi  = (const float*)d_in[3];
    const float* bi  = (const float*)d_in[4];
    const float* W1  = (const float*)d_in[5];
    const float* b1  = (const float*)d_in[6];
    const float* W2  = (const float*)d_in[7];
    const float* b2  = (const float*)d_in[8];
    const float* W3  = (const float*)d_in[9];
    const float* b3  = (const float*)d_in[10];
    const float* bl[3] = { b1, b2, b3 };
    float* out = (float*)d_out;  // (4, N, HID)

    const int* src = ei;
    const int* tgt = ei + N_EDGES;

    // Workspace layout (per-node padded edge array; hbf double-buffered).
    int2* binned = (int2*)d_ws;                                      // N*CAP_N*8B = 51.2 MB
    int* cnt = (int*)(binned + (size_t)N_NODES * CAP_N);             // N ints
    __hip_bfloat16* hbf0 = (__hip_bfloat16*)(cnt + N_NODES);         // N*HID bf16
    __hip_bfloat16* hbf1 = hbf0 + (size_t)N_NODES * HID;             // N*HID bf16
    unsigned short* wf_in  = (unsigned short*)(hbf1 + (size_t)N_NODES * HID);
    unsigned short* wf_hid = wf_in + 8192;                           // 3 x 4096

    const int prep_blocks = (N_NODES + 255) / 256;  // 391: covers counter init
    wf_prep_kernel<<<prep_blocks, 256, 0, stream>>>(Wi, W1, W2, W3,
                                                    wf_in, wf_hid, cnt);

    const int sc_blocks = (N_EDGES + 255) / 256;    // 6250
    scatter_direct_kernel<<<sc_blocks, 256, 0, stream>>>(src, tgt, ea, cnt, binned);

    const int gemm_blocks = (N_NODES + 63) / 64;    // 1563
    gemm_in_kernel<<<gemm_blocks, 256, 0, stream>>>(x, wf_in, bi, out, hbf0);

    __hip_bfloat16* hin  = hbf0;
    __hip_bfloat16* hout = hbf1;
    for (int l = 0; l < 3; ++l) {
        const float* hl = out + (size_t)l * N_NODES * HID;
        float* hn       = out + (size_t)(l + 1) * N_NODES * HID;
        agg_gemm_kernel<<<gemm_blocks, 256, 0, stream>>>(
            hl, hin, cnt, binned,
            wf_hid + (size_t)l * 4096, bl[l], hn, hout, (l < 2) ? 1 : 0);
        __hip_bfloat16* t = hin; hin = hout; hout = t;
    }
}

// Round 8
// 397.698 us; speedup vs baseline: 5.2081x; 1.0297x over previous
//
#include <hip/hip_runtime.h>
#include <hip/hip_bf16.h>

#define N_NODES 100000
#define N_EDGES 1600000
#define IN_DIM  128
#define HID     64
#define CAP_N   64         // padded per-NODE capacity (avg degree 16, P(deg>=64)~1e-18)
#define CNT_STRIDE 16      // one 4B counter per 64B line (atomic same-line spread)

#define SC_EB   1024       // edges per scatter block (4/thread)
#define SC_BLOCKS ((N_EDGES + SC_EB - 1) / SC_EB)   // 1563
#define GEMM_BLOCKS ((N_NODES + 63) / 64)           // 1563

#define PITCH_IN  152      // bf16 units per LDS row for K=128 (gemm_in staging)
#define PITCH_HID 88       // bf16 units per LDS row for K=64  (agg staging)

typedef __attribute__((ext_vector_type(8))) short bf16x8;   // MFMA A/B frag (4 VGPRs)
typedef __attribute__((ext_vector_type(4))) float f32x4;    // MFMA C/D frag

__device__ inline unsigned short f2bf(float f) {
    __hip_bfloat16 b = __float2bfloat16(f);
    return *reinterpret_cast<unsigned short*>(&b);
}

// ---------------------------------------------------------------------------
// Pre-pack W matrices into B-fragment order bf16 + zero per-node counters
// (padded: one counter per 64B line).
// flat = (((kc*4 + nt)*4 + quad)*16 + n16)*8 + j ;  k = kc*32+quad*8+j, n = nt*16+n16
// ---------------------------------------------------------------------------
__global__ void wf_prep_kernel(const float* __restrict__ Wi,
                               const float* __restrict__ W1,
                               const float* __restrict__ W2,
                               const float* __restrict__ W3,
                               unsigned short* __restrict__ wf_in,
                               unsigned short* __restrict__ wf_hid,
                               int* __restrict__ cnt) {
    int t = blockIdx.x * 256 + threadIdx.x;
    if (t < N_NODES) cnt[(size_t)t * CNT_STRIDE] = 0;
    if (t < 8192) {  // Wi: K=128 -> kc in 0..3
        int j = t & 7, n16 = (t >> 3) & 15, quad = (t >> 7) & 3, nt = (t >> 9) & 3, kc = t >> 11;
        int k = kc * 32 + quad * 8 + j, n = nt * 16 + n16;
        wf_in[t] = f2bf(Wi[k * HID + n]);
    }
    if (t < 4096) {  // W1..W3: K=64 -> kc in 0..1
        int j = t & 7, n16 = (t >> 3) & 15, quad = (t >> 7) & 3, nt = (t >> 9) & 3, kc = t >> 11;
        int k = kc * 32 + quad * 8 + j, n = nt * 16 + n16;
        wf_hid[t]        = f2bf(W1[k * HID + n]);
        wf_hid[4096 + t] = f2bf(W2[k * HID + n]);
        wf_hid[8192 + t] = f2bf(W3[k * HID + n]);
    }
}

// ---------------------------------------------------------------------------
// FUSED prep: even blocks scatter edges (atomic/latency-bound, no LDS, no
// VALU, no BW), odd blocks run h0 = relu(x@Wi+bi) (MFMA/BW-bound). The bid&1
// interleave puts a uniform mix of both wave types on every CU, so the gemm
// hides inside the scatter's memory-latency slack.
// Scatter: binned[tgt*CAP_N + r] = (src, w_bits); r from a padded per-node
// atomic counter (1 per 64B line -> 16 not 256 same-line RMWs). 4 independent
// edges per thread = 4 atomic chains in flight.
// ---------------------------------------------------------------------------
__global__ __launch_bounds__(256) void fused_scatter_gemm_kernel(
        const int* __restrict__ src,
        const int* __restrict__ tgt,
        const float* __restrict__ ea,
        int* __restrict__ cnt,
        int2* __restrict__ binned,
        const float* __restrict__ x,
        const unsigned short* __restrict__ wf,
        const float* __restrict__ bi,
        float* __restrict__ h0,
        __hip_bfloat16* __restrict__ hbf) {
    __shared__ unsigned short sX[64 * PITCH_IN];   // 19456 B (gemm branch only)
    const int tid = threadIdx.x;

    if ((blockIdx.x & 1) == 0) {
        // ================= scatter branch =================
        const int s  = blockIdx.x >> 1;
        const int e0 = s * SC_EB;
        #pragma unroll
        for (int k = 0; k < SC_EB / 256; ++k) {
            int e = e0 + tid + k * 256;
            if (e < N_EDGES) {
                int t = tgt[e];
                int r = atomicAdd(&cnt[(size_t)t * CNT_STRIDE], 1);
                if (r < CAP_N)   // overflow guard (P ~ 1e-13)
                    binned[(size_t)t * CAP_N + r] =
                        make_int2(src[e], __float_as_int(ea[e]));
            }
        }
        return;
    }

    // ================= gemm_in branch =================
    const int row0 = (blockIdx.x >> 1) * 64;

    // Stage x tile (64 x 128 f32 -> bf16), coalesced float4 reads, 8B LDS writes.
    #pragma unroll
    for (int it = 0; it < 8; ++it) {
        int i  = tid + it * 256;
        int r  = i >> 5;        // 32 float4 per row
        int kq = i & 31;
        int rg = row0 + r;
        float4 v = (rg < N_NODES)
                 ? ((const float4*)x)[(size_t)rg * (IN_DIM / 4) + kq]
                 : make_float4(0.f, 0.f, 0.f, 0.f);
        ushort4 pk;
        pk.x = f2bf(v.x); pk.y = f2bf(v.y); pk.z = f2bf(v.z); pk.w = f2bf(v.w);
        *(ushort4*)(sX + r * PITCH_IN + kq * 4) = pk;
    }
    __syncthreads();

    const int lane = tid & 63;
    const int wid  = tid >> 6;
    const int l16  = lane & 15;
    const int q    = lane >> 4;

    f32x4 acc[4] = {{0,0,0,0},{0,0,0,0},{0,0,0,0},{0,0,0,0}};
    const bf16x8* wf8 = (const bf16x8*)wf;

    #pragma unroll
    for (int kc = 0; kc < 4; ++kc) {
        bf16x8 af = *(const bf16x8*)(sX + (wid * 16 + l16) * PITCH_IN + kc * 32 + q * 8);
        #pragma unroll
        for (int nt = 0; nt < 4; ++nt) {
            bf16x8 bfr = wf8[((kc * 4 + nt) * 4 + q) * 16 + l16];
            acc[nt] = __builtin_amdgcn_mfma_f32_16x16x32_bf16(af, bfr, acc[nt], 0, 0, 0);
        }
    }

    // Epilogue: C/D layout col = lane&15, row = quad*4 + reg  [m89]
    #pragma unroll
    for (int nt = 0; nt < 4; ++nt) {
        float bb = bi[nt * 16 + l16];
        #pragma unroll
        for (int reg = 0; reg < 4; ++reg) {
            int rg = row0 + wid * 16 + q * 4 + reg;
            if (rg < N_NODES) {
                float v = fmaxf(acc[nt][reg] + bb, 0.0f);
                h0 [(size_t)rg * HID + nt * 16 + l16] = v;
                hbf[(size_t)rg * HID + nt * 16 + l16] = __float2bfloat16(v);
            }
        }
    }
}

// ---------------------------------------------------------------------------
// FUSED: a = h + segment_sum(bf16(h)[src] * w) ; hnext = relu(a @ W + b).
// R4's proven pull-mode structure reading the per-node PADDED edge array
// (beg = node*CAP_N): no offs, no pairs, no sort anywhere.
// ---------------------------------------------------------------------------
__global__ __launch_bounds__(256) void agg_gemm_kernel(
        const float* __restrict__ h,               // layer-l activations (f32)
        const __hip_bfloat16* __restrict__ hbf_in, // layer-l activations (bf16)
        const int* __restrict__ cnt,
        const int2* __restrict__ binned,
        const unsigned short* __restrict__ wf,     // fragment-order W (bf16 bits)
        const float* __restrict__ b,
        float* __restrict__ hnext,
        __hip_bfloat16* __restrict__ hbf_out,
        const int store_bf) {
    __shared__ unsigned short sXs[64 * PITCH_HID]; // 11264 B
    const int tid  = threadIdx.x;
    const int row0 = blockIdx.x * 64;
    const int lane = tid & 63;
    const int wid  = tid >> 6;
    const int grp  = lane >> 4;
    const int sub  = lane & 15;

    const int node0 = row0 + wid * 16;

    // Counts for this wave's 16 nodes: lanes 0-15 load, shfl-broadcast.
    int cv = 0;
    {
        int nl = node0 + (lane & 15);
        if (lane < 16 && nl < N_NODES)
            cv = min(cnt[(size_t)nl * CNT_STRIDE], CAP_N);
    }

    // Prefetch node0's pair block (clamped: only lines covering [0,cnt) fetched).
    int c0 = __shfl(cv, 0);
    int2 pl = binned[(size_t)min(node0, N_NODES - 1) * CAP_N + min(lane, max(c0 - 1, 0))];

    // ---- Phase 1: aggregate 16 nodes per wave into LDS (bf16) ----
    for (int t = 0; t < 16; ++t) {
        const int node = node0 + t;                // wave-uniform
        const int ccur = __shfl(cv, t);
        const int2 pl_cur = pl;
        if (t < 15) {                              // prefetch next node's pairs
            int cn = __shfl(cv, t + 1);
            pl = binned[(size_t)min(node + 1, N_NODES - 1) * CAP_N
                        + min(lane, max(cn - 1, 0))];
        }
        if (node < N_NODES) {
            float ax = 0.f, ay = 0.f, az = 0.f, aw = 0.f;
            const int last = ccur - 1;
            for (int i = 0; i < ccur; i += 8) {
                int e0 = i + grp;
                int e1 = i + 4 + grp;
                bool l0 = (e0 <= last);
                bool l1 = (e1 <= last);
                int s0  = __shfl(pl_cur.x, l0 ? e0 : last);
                int w0i = __shfl(pl_cur.y, l0 ? e0 : last);
                int s1  = __shfl(pl_cur.x, l1 ? e1 : last);
                int w1i = __shfl(pl_cur.y, l1 ? e1 : last);
                uint2 g0 = *(const uint2*)(hbf_in + (size_t)s0 * HID + sub * 4);
                uint2 g1 = *(const uint2*)(hbf_in + (size_t)s1 * HID + sub * 4);
                float w0 = l0 ? __int_as_float(w0i) : 0.0f;
                float w1 = l1 ? __int_as_float(w1i) : 0.0f;
                ax += w0 * __uint_as_float(g0.x << 16);
                ay += w0 * __uint_as_float(g0.x & 0xFFFF0000u);
                az += w0 * __uint_as_float(g0.y << 16);
                aw += w0 * __uint_as_float(g0.y & 0xFFFF0000u);
                ax += w1 * __uint_as_float(g1.x << 16);
                ay += w1 * __uint_as_float(g1.x & 0xFFFF0000u);
                az += w1 * __uint_as_float(g1.y << 16);
                aw += w1 * __uint_as_float(g1.y & 0xFFFF0000u);
            }
            ax += __shfl_xor(ax, 16); ay += __shfl_xor(ay, 16);
            az += __shfl_xor(az, 16); aw += __shfl_xor(aw, 16);
            ax += __shfl_xor(ax, 32); ay += __shfl_xor(ay, 32);
            az += __shfl_xor(az, 32); aw += __shfl_xor(aw, 32);
            if (grp == 0) {
                const float4 hv = *(const float4*)(h + (size_t)node * HID + sub * 4);
                ushort4 pk;
                pk.x = f2bf(hv.x + ax); pk.y = f2bf(hv.y + ay);
                pk.z = f2bf(hv.z + az); pk.w = f2bf(hv.w + aw);
                *(ushort4*)(sXs + (wid * 16 + t) * PITCH_HID + sub * 4) = pk;
            }
        } else if (grp == 0) {
            ushort4 z; z.x = 0; z.y = 0; z.z = 0; z.w = 0;
            *(ushort4*)(sXs + (wid * 16 + t) * PITCH_HID + sub * 4) = z;
        }
    }
    __syncthreads();

    // ---- Phase 2: 16x16x32 bf16 MFMA (K=64) + relu epilogue ----
    const int l16 = lane & 15;
    const int q   = lane >> 4;

    f32x4 acc[4] = {{0,0,0,0},{0,0,0,0},{0,0,0,0},{0,0,0,0}};
    const bf16x8* wf8 = (const bf16x8*)wf;

    #pragma unroll
    for (int kc = 0; kc < 2; ++kc) {
        bf16x8 af = *(const bf16x8*)(sXs + (wid * 16 + l16) * PITCH_HID + kc * 32 + q * 8);
        #pragma unroll
        for (int nt = 0; nt < 4; ++nt) {
            bf16x8 bfr = wf8[((kc * 4 + nt) * 4 + q) * 16 + l16];
            acc[nt] = __builtin_amdgcn_mfma_f32_16x16x32_bf16(af, bfr, acc[nt], 0, 0, 0);
        }
    }

    #pragma unroll
    for (int nt = 0; nt < 4; ++nt) {
        float bb = b[nt * 16 + l16];
        #pragma unroll
        for (int reg = 0; reg < 4; ++reg) {
            int rg = row0 + wid * 16 + q * 4 + reg;
            if (rg < N_NODES) {
                float v = fmaxf(acc[nt][reg] + bb, 0.0f);
                hnext[(size_t)rg * HID + nt * 16 + l16] = v;
                if (store_bf)
                    hbf_out[(size_t)rg * HID + nt * 16 + l16] = __float2bfloat16(v);
            }
        }
    }
}

extern "C" void kernel_launch(void* const* d_in, const int* in_sizes, int n_in,
                              void* d_out, int out_size, void* d_ws, size_t ws_size,
                              hipStream_t stream) {
    const float* x   = (const float*)d_in[0];
    const int*   ei  = (const int*)  d_in[1];   // (2, E): [src | tgt]
    const float* ea  = (const float*)d_in[2];
    const float* Wi  = (const float*)d_in[3];
    const float* bi  = (const float*)d_in[4];
    const float* W1  = (const float*)d_in[5];
    const float* b1  = (const float*)d_in[6];
    const float* W2  = (const float*)d_in[7];
    const float* b2  = (const float*)d_in[8];
    const float* W3  = (const float*)d_in[9];
    const float* b3  = (const float*)d_in[10];
    const float* bl[3] = { b1, b2, b3 };
    float* out = (float*)d_out;  // (4, N, HID)

    const int* src = ei;
    const int* tgt = ei + N_EDGES;

    // Workspace layout (per-node padded edge array; padded counters;
    // hbf double-buffered).
    int2* binned = (int2*)d_ws;                                      // N*CAP_N*8B = 51.2 MB
    int* cnt = (int*)(binned + (size_t)N_NODES * CAP_N);             // N*16 ints (6.4 MB)
    __hip_bfloat16* hbf0 = (__hip_bfloat16*)(cnt + (size_t)N_NODES * CNT_STRIDE);
    __hip_bfloat16* hbf1 = hbf0 + (size_t)N_NODES * HID;             // N*HID bf16
    unsigned short* wf_in  = (unsigned short*)(hbf1 + (size_t)N_NODES * HID);
    unsigned short* wf_hid = wf_in + 8192;                           // 3 x 4096

    const int prep_blocks = (N_NODES + 255) / 256;  // 391: covers counter init
    wf_prep_kernel<<<prep_blocks, 256, 0, stream>>>(Wi, W1, W2, W3,
                                                    wf_in, wf_hid, cnt);

    fused_scatter_gemm_kernel<<<SC_BLOCKS + GEMM_BLOCKS, 256, 0, stream>>>(
        src, tgt, ea, cnt, binned, x, wf_in, bi, out, hbf0);

    __hip_bfloat16* hin  = hbf0;
    __hip_bfloat16* hout = hbf1;
    for (int l = 0; l < 3; ++l) {
        const float* hl = out + (size_t)l * N_NODES * HID;
        float* hn       = out + (size_t)(l + 1) * N_NODES * HID;
        agg_gemm_kernel<<<GEMM_BLOCKS, 256, 0, stream>>>(
            hl, hin, cnt, binned,
            wf_hid + (size_t)l * 4096, bl[l], hn, hout, (l < 2) ? 1 : 0);
        __hip_bfloat16* t = hin; hin = hout; hout = t;
    }
}